// Round 2
// 573.937 us; speedup vs baseline: 1.0190x; 1.0190x over previous
//
#include <hip/hip_runtime.h>

// OuterProduct: out[b, c,    i, j] = |seq1[b,c,i] - seq2[b,c,j]|   (c in [0,64))
//               out[b, 64+c, i, j] =  seq1[b,c,i] * seq2[b,c,j]
// B=8, C=64, L=384. Output [8,128,384,384] fp32 = 604 MB; inputs 1.5 MB
// (cache-resident) -> pure write-BW bound. Roofline ~= 604 MB / 6.2 TB/s ~= 97 us.
//
// R2 == R1 resubmit (R1 bench died: "MI355X container failed twice" — infra,
// no kernel signal). Changes vs prior best (585 us bench / ~195 us kernel):
//  1. PLAIN stores instead of __builtin_nontemporal_store. The harness's own
//     fillBuffer hits 6.2 TB/s pure-write with write-back stores; our NT kernel
//     only managed ~3.1 TB/s. Full-line f4 stores have no RFO fetch cost, so
//     the NT hint buys nothing and (theory) throttles the write path.
//  2. Fuse both output halves per thread: same s1/s2 feed |s1-s2| and s1*s2.
//     Halves thread count + index math + input loads; 2 independent store
//     streams per thread (both perfectly coalesced per wave).
//
// Index algebra: idx = ((b*64+c)*384 + i)*96 + j4
//   s1 flat index   = idx/96
//   abs-half f4 off = ((b*128+c)*384+i)*96+j4 = idx + b*64*384*96
//   mul-half f4 off = abs off + 64*384*96
// Max f4 offset = 37,748,735 < 2^31 — int math safe.

#define L_DIM 384
#define J4    96
#define HALF_STRIDE_F4 (64 * 384 * 96)   // 2,359,296 f4 elems between halves

typedef float f4 __attribute__((ext_vector_type(4)));

__global__ __launch_bounds__(256) void outer_product_kernel(
    const float* __restrict__ seq1,
    const float* __restrict__ seq2,
    float* __restrict__ out,
    int n_pairs)
{
    int idx = blockIdx.x * 256 + threadIdx.x;
    if (idx >= n_pairs) return;

    int t  = idx / J4;           // = (b*64+c)*384 + i  == flat s1 index
    int j4 = idx - t * J4;
    int bc = t / L_DIM;          // b*64 + c
    int b  = bc >> 6;

    float s1 = seq1[t];
    f4 s2 = *(const f4*)(seq2 + bc * L_DIM + j4 * 4);

    f4 m = s1 * s2;
    f4 d = s1 - s2;
    f4 a;
    a.x = fabsf(d.x);
    a.y = fabsf(d.y);
    a.z = fabsf(d.z);
    a.w = fabsf(d.w);

    int o = idx + b * HALF_STRIDE_F4;    // abs-half f4 offset
    f4* o4 = (f4*)out;
    o4[o]                  = a;
    o4[o + HALF_STRIDE_F4] = m;
}

extern "C" void kernel_launch(void* const* d_in, const int* in_sizes, int n_in,
                              void* d_out, int out_size, void* d_ws, size_t ws_size,
                              hipStream_t stream)
{
    const float* seq1 = (const float*)d_in[0];
    const float* seq2 = (const float*)d_in[1];
    float* out = (float*)d_out;

    int n_pairs = out_size / 8;              // 18,874,368 (each thread: 2 f4)
    int grid = (n_pairs + 255) / 256;        // 73,728 blocks
    outer_product_kernel<<<grid, 256, 0, stream>>>(seq1, seq2, out, n_pairs);
}